// Round 5
// baseline (215.730 us; speedup 1.0000x reference)
//
#include <hip/hip_runtime.h>
#include <math.h>

#define N 512
#define C 157
#define M 20
#define RH0 79          // rows in half 0
#define TILE_MAX (RH0 * C)   // 12403 floats = 49,612 B

__device__ __forceinline__ float sigmoidf_(float x) {
    return 1.0f / (1.0f + __expf(-x));
}

__device__ __forceinline__ void async_cp16(const float* g, float* l) {
    __builtin_amdgcn_global_load_lds(
        (const __attribute__((address_space(1))) void*)g,
        (__attribute__((address_space(3))) void*)l, 16, 0, 0);
}

// ws layout (floats)
#define WS_CP 0                    // colpart [N*2*C]
#define WS_RS (N * 2 * C)          // rowsum  [N*C]
#define WS_LP (WS_RS + N * C)      // loss_part [N]

// Kernel A: grid = N*2 (n, half), 512 threads.
// Stages half of aa[n] into LDS (async), computes msg/fmsg, then both einsum
// partials from LDS with conflict-free access (stride 157, gcd(29,32)=1).
__global__ __launch_bounds__(512) void atf_einsum_kernel(
    const float* __restrict__ aa,
    const float* __restrict__ bank_values,
    const int* __restrict__ bank_times,
    const int* __restrict__ bank_mask,
    const int* __restrict__ ids,
    const int* __restrict__ times,
    float* __restrict__ ws)
{
    const int n   = blockIdx.x >> 1;
    const int h   = blockIdx.x & 1;
    const int i0  = h * RH0;
    const int RH  = h ? (C - RH0) : RH0;      // 78 : 79
    const int len = RH * C;

    const int tid  = threadIdx.x;
    const int wave = tid >> 6;
    const int lane = tid & 63;

    __shared__ float tile[TILE_MAX];   // 49,612 B
    __shared__ float s_msg[C];
    __shared__ float s_fmsg[C];
    __shared__ float s_colp[3][C];
    __shared__ float s_rowp[3][RH0];

    const int   id = ids[n];
    const float t0 = (float)times[n];
    const float* aan = aa + (size_t)n * C * C + i0 * C;

    // ---- issue async staging: 1024B chunks (256 floats per wave-instr) ----
    const int full = len >> 8;
    for (int c = wave; c < full; c += 8) {
        async_cp16(aan + (c << 8) + lane * 4, &tile[c << 8]);
    }
    {   // tail (<256 floats): regular load + ds_write
        const int idx = (full << 8) + tid;
        if (idx < len) tile[idx] = aan[idx];
    }

    // ---- phase 1 (overlaps staging): msg / fmsg, no barrier needed before ----
    if (tid < C) {
        const float inv2s2 = 1.0f / (2.0f * 300.0f * 300.0f);
        const float INVDEC = 1.0f / 0.9f;
        float accP = 0.f, accF = 0.f, denP = 0.f, denF = 0.f;
        float wP = 1.f, wF = 1.f;
        const float* vb = bank_values + (size_t)id * M * C + tid;
        const int* tsrow = bank_times + (size_t)id * M;   // uniform -> s_load, L1-hot
        const int* mkrow = bank_mask + (size_t)id * M;
        #pragma unroll
        for (int m = 0; m < M; ++m) {
            const float ts = (float)tsrow[m];
            const float d  = ts - t0;
            const float kern = __expf(-d * d * inv2s2);
            const float v = vb[m * C];
            const bool mk = (mkrow[m] != 0);
            if (mk && ts < t0) { accP += wP * kern * v; denP += wP; wP *= INVDEC; }
            if (mk && ts > t0) { accF += wF * kern * v; denF += wF; wF *= INVDEC; }
        }
        s_msg[tid]  = (denP > 0.f) ? accP / fmaxf(denP, 1e-7f) : 0.0f;
        s_fmsg[tid] = (denF > 0.f) ? accF / fmaxf(denF, 1e-7f) : 0.0f;
    }

    __syncthreads();   // drains staging vmcnt + publishes msg/fmsg

    // ---- col partials: thread (j, seg) sums over its row range ----
    if (tid < 3 * C) {
        const int j   = tid % C;
        const int seg = tid / C;
        const int r0 = (seg * RH) / 3, r1 = ((seg + 1) * RH) / 3;
        float acc = 0.f;
        for (int r = r0; r < r1; ++r) acc += tile[r * C + j] * s_msg[i0 + r];
        s_colp[seg][j] = acc;
    }
    // ---- row sums: thread (r, seg) sums over its j range ----
    if (tid < 3 * RH) {
        const int r   = tid % RH;
        const int seg = tid / RH;
        const int j0 = (seg * C) / 3, j1 = ((seg + 1) * C) / 3;
        float acc = 0.f;
        for (int j = j0; j < j1; ++j) acc += tile[r * C + j] * s_fmsg[j];
        s_rowp[seg][r] = acc;
    }
    __syncthreads();

    // ---- write partials to ws ----
    if (tid < C) {
        ws[WS_CP + ((size_t)(2 * n + h)) * C + tid] =
            s_colp[0][tid] + s_colp[1][tid] + s_colp[2][tid];
    }
    if (tid < RH) {
        ws[WS_RS + (size_t)n * C + i0 + tid] =
            s_rowp[0][tid] + s_rowp[1][tid] + s_rowp[2][tid];
    }
}

// Kernel B: epilogue per n — qa, BCE partials.
__global__ __launch_bounds__(256) void atf_epilogue_kernel(
    const float* __restrict__ a,
    const float* __restrict__ target,
    const float* __restrict__ ws,
    float* __restrict__ out,
    float* __restrict__ loss_part)
{
    const int n    = blockIdx.x;
    const int tid  = threadIdx.x;
    const int wave = tid >> 6;
    const int lane = tid & 63;
    __shared__ float s_red[4];

    float local = 0.0f;
    if (tid < C) {
        const float colsum = ws[WS_CP + ((size_t)(2 * n)) * C + tid]
                           + ws[WS_CP + ((size_t)(2 * n + 1)) * C + tid];
        const float rowsum = ws[WS_RS + (size_t)n * C + tid];
        const float av = a[(size_t)n * C + tid];
        const float qlin = av + colsum + rowsum;
        const float p = sigmoidf_(qlin);
        out[(size_t)n * C + tid] = p;

        const float t = target[(size_t)n * C + tid];
        float pc = fminf(fmaxf(p, 1e-7f), 1.0f - 1e-7f);
        float pa = sigmoidf_(av);
        pa = fminf(fmaxf(pa, 1e-7f), 1.0f - 1e-7f);
        local = t * logf(pc) + (1.0f - t) * logf(1.0f - pc)
              + t * logf(pa) + (1.0f - t) * logf(1.0f - pa);
    }
    #pragma unroll
    for (int off = 32; off > 0; off >>= 1) local += __shfl_down(local, off, 64);
    if (lane == 0) s_red[wave] = local;
    __syncthreads();
    if (tid == 0) loss_part[n] = s_red[0] + s_red[1] + s_red[2] + s_red[3];
}

__global__ __launch_bounds__(256) void atf_finalize_kernel(
    const float* __restrict__ loss_part,
    float* __restrict__ out)
{
    const int tid  = threadIdx.x;
    const int wave = tid >> 6;
    const int lane = tid & 63;
    __shared__ double s_red[4];

    double local = (double)loss_part[tid] + (double)loss_part[tid + 256];
    #pragma unroll
    for (int off = 32; off > 0; off >>= 1) local += __shfl_down(local, off, 64);
    if (lane == 0) s_red[wave] = local;
    __syncthreads();
    if (tid == 0) {
        const double s = s_red[0] + s_red[1] + s_red[2] + s_red[3];
        out[N * C] = (float)(-s / ((double)(N * C) * 3.0));
    }
}

extern "C" void kernel_launch(void* const* d_in, const int* in_sizes, int n_in,
                              void* d_out, int out_size, void* d_ws, size_t ws_size,
                              hipStream_t stream) {
    const float* a           = (const float*)d_in[0];
    const float* aa          = (const float*)d_in[1];
    const float* target      = (const float*)d_in[2];
    const float* bank_values = (const float*)d_in[3];
    const int*   bank_times  = (const int*)d_in[4];
    const int*   bank_mask   = (const int*)d_in[5];
    const int*   ids         = (const int*)d_in[6];
    const int*   times       = (const int*)d_in[7];

    float* out = (float*)d_out;
    float* ws  = (float*)d_ws;

    atf_einsum_kernel<<<N * 2, 512, 0, stream>>>(aa, bank_values, bank_times,
                                                 bank_mask, ids, times, ws);
    atf_epilogue_kernel<<<N, 256, 0, stream>>>(a, target, ws, out, ws + WS_LP);
    atf_finalize_kernel<<<1, 256, 0, stream>>>(ws + WS_LP, out);
}